// Round 3
// baseline (138.770 us; speedup 1.0000x reference)
//
#include <hip/hip_runtime.h>
#include <math.h>

#define RT_EPS 1e-4f
#define BLK 256

// One ray: camera transform, first sphere hit, direct point-light eval.
// Secondary bounces provably never hit (convex sphere, outward hemisphere
// ray from p + EPS*n => b >= 0, c ~ 2*EPS > 0 => no positive root), so the
// reference's depth-1..3 iterations contribute exactly zero to both outputs;
// u_bsdf never affects the result.
__device__ __forceinline__ float4 trace_ray(
    float ox, float oy, float oz,
    float dx, float dy, float dz,
    float cx, float cy, float cz)
{
    // o = ray_o*0.5 + (0,0,-4);  d = normalize(ray_d*0.2 + (0,0,1))
    ox *= 0.5f;
    oy *= 0.5f;
    oz = oz * 0.5f - 4.0f;
    dx *= 0.2f;
    dy *= 0.2f;
    dz = dz * 0.2f + 1.0f;
    float dd = dx * dx + dy * dy + dz * dz;
    float dinv = __builtin_amdgcn_rsqf(fmaxf(dd, 1e-24f));  // 1/max(|d|,1e-12)
    dx *= dinv; dy *= dinv; dz *= dinv;

    // Unit sphere at origin
    float b = ox * dx + oy * dy + oz * dz;
    float c = ox * ox + oy * oy + oz * oz - 1.0f;
    float disc = b * b - c;
    float sq = __builtin_amdgcn_sqrtf(fmaxf(disc, 0.0f));
    float t0 = -b - sq;
    float t1 = -b + sq;
    float t = (t0 > RT_EPS) ? t0 : t1;
    bool hit = (disc > 0.0f) && (t > RT_EPS);

    float px = ox + t * dx;
    float py = oy + t * dy;
    float pz = oz + t * dz;
    float pp = px * px + py * py + pz * pz;
    float ninv = __builtin_amdgcn_rsqf(fmaxf(pp, 1e-24f));
    float nx = px * ninv, ny = py * ninv, nz = pz * ninv;

    // Point light at (3,4,5): result = albedo * (cos_l/pi) * light / dist2
    float tlx = 3.0f - px, tly = 4.0f - py, tlz = 5.0f - pz;
    float dist2 = tlx * tlx + tly * tly + tlz * tlz;
    float rinv = __builtin_amdgcn_rsqf(dist2);
    float cos_l = fmaxf((tlx * nx + tly * ny + tlz * nz) * rinv, 0.0f);
    float k = cos_l * __builtin_amdgcn_rcpf(dist2);

    float4 r;
    r.x = hit ? cx * k : 0.0f;
    r.y = hit ? cy * k : 0.0f;
    r.z = hit ? cz * k : 0.0f;
    r.w = hit ? 1.0f : 0.0f;   // original_active
    return r;
}

__global__ __launch_bounds__(256) void path_trace_kernel(
    const float4* __restrict__ ro4,   // ray_o as float4 (3 per 4 rays)
    const float4* __restrict__ rd4,   // ray_d as float4
    const float* __restrict__ albedo, // (3,)
    const float* __restrict__ light,  // (3,)
    float4* __restrict__ res4,        // result as float4 (3 per 4 rays)
    float4* __restrict__ act4,        // original_active (1 float4 per 4 rays)
    int nq)                           // N/4
{
    // LDS transpose staging: global accesses stay lane-linear (fully
    // coalesced); the stride-48B AoS access happens in LDS where the bank
    // pattern (12*i mod 32) is conflict-free per 8-lane group.
    __shared__ float4 sA[3 * BLK];
    __shared__ float4 sB[3 * BLK];

    int tid = threadIdx.x;
    int qbase = blockIdx.x * BLK;
    size_t gb3 = (size_t)3 * qbase;
    size_t lim = (size_t)3 * nq;

    #pragma unroll
    for (int k = 0; k < 3; ++k) {
        size_t idx = gb3 + k * BLK + tid;
        if (idx < lim) {
            sA[k * BLK + tid] = ro4[idx];
            sB[k * BLK + tid] = rd4[idx];
        }
    }
    __syncthreads();

    float4 a0 = sA[3 * tid + 0];
    float4 a1 = sA[3 * tid + 1];
    float4 a2 = sA[3 * tid + 2];
    float4 b0 = sB[3 * tid + 0];
    float4 b1 = sB[3 * tid + 1];
    float4 b2 = sB[3 * tid + 2];

    // Wave-uniform constants (scalar loads)
    const float inv_pi = 0.31830988618379067154f;
    float cx = albedo[0] * light[0] * inv_pi;
    float cy = albedo[1] * light[1] * inv_pi;
    float cz = albedo[2] * light[2] * inv_pi;

    float4 r0 = trace_ray(a0.x, a0.y, a0.z, b0.x, b0.y, b0.z, cx, cy, cz);
    float4 r1 = trace_ray(a0.w, a1.x, a1.y, b0.w, b1.x, b1.y, cx, cy, cz);
    float4 r2 = trace_ray(a1.z, a1.w, a2.x, b1.z, b1.w, b2.x, cx, cy, cz);
    float4 r3 = trace_ray(a2.y, a2.z, a2.w, b2.y, b2.z, b2.w, cx, cy, cz);

    // Transpose results back through LDS for coalesced stores
    __syncthreads();
    sA[3 * tid + 0] = make_float4(r0.x, r0.y, r0.z, r1.x);
    sA[3 * tid + 1] = make_float4(r1.y, r1.z, r2.x, r2.y);
    sA[3 * tid + 2] = make_float4(r2.z, r3.x, r3.y, r3.z);
    __syncthreads();

    #pragma unroll
    for (int k = 0; k < 3; ++k) {
        size_t idx = gb3 + k * BLK + tid;
        if (idx < lim) res4[idx] = sA[k * BLK + tid];
    }
    int q = qbase + tid;
    if (q < nq) act4[q] = make_float4(r0.w, r1.w, r2.w, r3.w);
}

extern "C" void kernel_launch(void* const* d_in, const int* in_sizes, int n_in,
                              void* d_out, int out_size, void* d_ws, size_t ws_size,
                              hipStream_t stream) {
    const float4* ro4   = (const float4*)d_in[0];
    const float4* rd4   = (const float4*)d_in[1];
    const float* albedo = (const float*)d_in[3];
    const float* light  = (const float*)d_in[4];
    float* out = (float*)d_out;

    int n = in_sizes[0] / 3;           // N rays (2097152, divisible by 4)
    int nq = n / 4;
    float4* res4 = (float4*)out;                    // 3N floats
    float4* act4 = (float4*)(out + (size_t)3 * n);  // N floats, 16B-aligned

    int block = BLK;
    int grid = (nq + block - 1) / block;
    path_trace_kernel<<<grid, block, 0, stream>>>(ro4, rd4, albedo, light,
                                                  res4, act4, nq);
}